// Round 1
// baseline (492.450 us; speedup 1.0000x reference)
//
#include <hip/hip_runtime.h>
#include <math.h>

#define HP 258
#define NPIX (HP*HP)          // 66564
#define C30 30
#define TOT (C30*NPIX)        // 1996920
#define LOGW 64

// ---------------- build padded fc channels (30 distinct, each x2 in ref) ----
// XP  = pad1(fc)   (xp for opening, operand+xp for dilation)
// OPN = pad1(-fc)  (operand for opening)
__global__ void build_fc_k(const float* __restrict__ logits,
                           float* __restrict__ xp, float* __restrict__ opn){
  int p = blockIdx.x*256 + threadIdx.x;
  if (p >= NPIX) return;
  int h = p / HP, w = p % HP;
  if (h==0 || h==HP-1 || w==0 || w==HP-1){
    #pragma unroll
    for (int c=0;c<C30;c++){ xp[c*NPIX+p] = 1.0f; opn[c*NPIX+p] = 1.0f; }
    return;
  }
  int oh = h-1, ow = w-1;
  // jax.image.resize bilinear, half-pixel centers, edge weights normalize == clamp
  float fy = 0.25f*oh - 0.375f;
  float fx = 0.25f*ow - 0.375f;
  float y0f = floorf(fy), x0f = floorf(fx);
  float ty = fy - y0f, tx = fx - x0f;
  int y0 = max(0, (int)y0f), y1 = min(LOGW-1, (int)y0f + 1);
  int x0 = max(0, (int)x0f), x1 = min(LOGW-1, (int)x0f + 1);
  float s[6];
  float m = -3.402823466e+38f;
  #pragma unroll
  for (int c=0;c<6;c++){
    const float* pl = logits + c*LOGW*LOGW;
    float v00 = pl[y0*LOGW + x0], v01 = pl[y0*LOGW + x1];
    float v10 = pl[y1*LOGW + x0], v11 = pl[y1*LOGW + x1];
    float a = v00 + (v01 - v00)*tx;
    float b = v10 + (v11 - v10)*tx;
    float v = a + (b - a)*ty;
    s[c] = v; m = fmaxf(m, v);
  }
  float sum = 0.0f;
  #pragma unroll
  for (int c=0;c<6;c++){ s[c] = expf(s[c]-m); sum += s[c]; }
  float inv = 1.0f/sum;
  #pragma unroll
  for (int c=0;c<6;c++) s[c] *= inv;
  #pragma unroll
  for (int c=0;c<C30;c++){
    int i = c/5, r = c%5;
    int j = r + (r>=i ? 1 : 0);      // itertools.permutations order
    float d = 0.5f*(s[i]-s[j]);
    float v = fmaxf(d, 0.0f);
    xp[c*NPIX+p]  = v;
    opn[c*NPIX+p] = -v;
  }
}

// ---------------- 3x3 pool (VALID) then pad1 with 1.0 ----------------------
template<int MAXP>
__global__ void pool_pad_k(const float* __restrict__ src, float* __restrict__ dst){
  int idx = blockIdx.x*256 + threadIdx.x;
  if (idx >= TOT) return;
  int c = idx / NPIX, p = idx % NPIX;
  int h = p / HP, w = p % HP;
  if (h==0 || h==HP-1 || w==0 || w==HP-1){ dst[idx] = 1.0f; return; }
  const float* s = src + (size_t)c*NPIX;
  if (MAXP){
    float mv = -3.402823466e+38f;
    #pragma unroll
    for (int dy=-1;dy<=1;dy++)
      #pragma unroll
      for (int dx=-1;dx<=1;dx++)
        mv = fmaxf(mv, s[(h+dy)*HP + (w+dx)]);
    dst[idx] = mv;
  } else {
    float a = 0.0f;
    #pragma unroll
    for (int dy=-1;dy<=1;dy++)
      #pragma unroll
      for (int dx=-1;dx<=1;dx++)
        a += s[(h+dy)*HP + (w+dx)];
    dst[idx] = a / 9.0f;
  }
}

// ---------------- batched fp32 matmul: C[ch] = A[ch] @ B[ch], 258x258 -------
__global__ __launch_bounds__(256) void matmul_k(const float* __restrict__ A,
                                                const float* __restrict__ B,
                                                float* __restrict__ C){
  __shared__ float As[16][65];
  __shared__ float Bs[16][65];
  int ch = blockIdx.z;
  const float* Ab = A + (size_t)ch*NPIX;
  const float* Bb = B + (size_t)ch*NPIX;
  float*       Cb = C + (size_t)ch*NPIX;
  int tid = threadIdx.x;
  int tx = tid & 15, ty = tid >> 4;
  int rowBase = blockIdx.x * 64;
  int colBase = blockIdx.y * 64;
  float acc[4][4] = {{0.f}};
  for (int k0 = 0; k0 < HP; k0 += 16){
    #pragma unroll
    for (int i=0;i<4;i++){
      int idx = tid + i*256;
      int ar = idx >> 4, ak = idx & 15;
      int gr = rowBase + ar, gk = k0 + ak;
      As[ak][ar] = (gr < HP && gk < HP) ? Ab[gr*HP + gk] : 0.0f;
    }
    #pragma unroll
    for (int i=0;i<4;i++){
      int idx = tid + i*256;
      int bk = idx >> 6, bn = idx & 63;
      int gk = k0 + bk, gc = colBase + bn;
      Bs[bk][bn] = (gk < HP && gc < HP) ? Bb[gk*HP + gc] : 0.0f;
    }
    __syncthreads();
    #pragma unroll
    for (int k=0;k<16;k++){
      float a0 = As[k][ty], a1 = As[k][ty+16], a2 = As[k][ty+32], a3 = As[k][ty+48];
      float b0 = Bs[k][tx], b1 = Bs[k][tx+16], b2 = Bs[k][tx+32], b3 = Bs[k][tx+48];
      acc[0][0] = fmaf(a0,b0,acc[0][0]); acc[0][1] = fmaf(a0,b1,acc[0][1]);
      acc[0][2] = fmaf(a0,b2,acc[0][2]); acc[0][3] = fmaf(a0,b3,acc[0][3]);
      acc[1][0] = fmaf(a1,b0,acc[1][0]); acc[1][1] = fmaf(a1,b1,acc[1][1]);
      acc[1][2] = fmaf(a1,b2,acc[1][2]); acc[1][3] = fmaf(a1,b3,acc[1][3]);
      acc[2][0] = fmaf(a2,b0,acc[2][0]); acc[2][1] = fmaf(a2,b1,acc[2][1]);
      acc[2][2] = fmaf(a2,b2,acc[2][2]); acc[2][3] = fmaf(a2,b3,acc[2][3]);
      acc[3][0] = fmaf(a3,b0,acc[3][0]); acc[3][1] = fmaf(a3,b1,acc[3][1]);
      acc[3][2] = fmaf(a3,b2,acc[3][2]); acc[3][3] = fmaf(a3,b3,acc[3][3]);
    }
    __syncthreads();
  }
  #pragma unroll
  for (int i=0;i<4;i++){
    int row = rowBase + ty + i*16;
    if (row >= HP) continue;
    #pragma unroll
    for (int j=0;j<4;j++){
      int col = colBase + tx + j*16;
      if (col < HP) Cb[(size_t)row*HP + col] = acc[i][j];
    }
  }
}

// ---------------- column mean over rows (axis=2) of (y - x) -----------------
__global__ void colmean_k(const float* __restrict__ y, const float* __restrict__ x,
                          float* __restrict__ cm){
  int c = blockIdx.y;
  int w = blockIdx.x*256 + threadIdx.x;
  if (w >= HP) return;
  const float* yb = y + (size_t)c*NPIX;
  const float* xb = x + (size_t)c*NPIX;
  float sum = 0.0f;
  for (int h=0; h<HP; h++) sum += yb[h*HP+w] - xb[h*HP+w];
  cm[c*HP + w] = sum / (float)HP;
}

// ---------------- rectification: out = x + relu((y-x) - colmean) ------------
__global__ void rectify_k(const float* __restrict__ x, const float* __restrict__ y,
                          const float* __restrict__ cm, float* __restrict__ out){
  int idx = blockIdx.x*256 + threadIdx.x;
  if (idx >= TOT) return;
  int c = idx / NPIX, p = idx % NPIX;
  int w = p % HP;
  float xv = x[idx];
  float off = y[idx] - xv - cm[c*HP + w];
  out[idx] = xv + fmaxf(off, 0.0f);
}

// ---------------- channel-normalize (60 ch == 2x the 30 distinct) -----------
__global__ void normalize_k(const float* __restrict__ oper, float* __restrict__ out){
  int p = blockIdx.x*256 + threadIdx.x;
  if (p >= NPIX) return;
  float ss = 0.0f;
  #pragma unroll
  for (int c=0;c<C30;c++){ float v = oper[c*NPIX+p]; ss = fmaf(v,v,ss); }
  float n = sqrtf(2.0f*ss);                // duplicate channels double sum-sq
  float inv = 1.0f / fmaxf(n, 1e-12f);
  #pragma unroll
  for (int c=0;c<C30;c++) out[c*NPIX+p] = oper[c*NPIX+p] * inv;
}

// ---------------- sum |a-b| -> deterministic per-block partials -------------
__global__ void absdiff_reduce_k(const float* __restrict__ a, const float* __restrict__ b,
                                 double* __restrict__ part){
  __shared__ double sd[256];
  int tid = threadIdx.x;
  size_t i = (size_t)blockIdx.x*256 + tid;
  size_t stride = (size_t)gridDim.x*256;
  double local = 0.0;
  for (; i < (size_t)TOT; i += stride) local += (double)fabsf(a[i]-b[i]);
  sd[tid] = local;
  __syncthreads();
  for (int s=128; s>0; s>>=1){ if (tid<s) sd[tid]+=sd[tid+s]; __syncthreads(); }
  if (tid==0) part[blockIdx.x] = sd[0];
}

// ---------------- final: |n_open - n_dil| + base_loss -----------------------
__global__ void finalize_k(const double* __restrict__ part,
                           const float* __restrict__ base, float* __restrict__ out){
  __shared__ double s0[256], s1[256];
  int tid = threadIdx.x;
  double l0=0.0, l1=0.0;
  for (int i=tid;i<1024;i+=256){ l0 += part[i]; l1 += part[1024+i]; }
  s0[tid]=l0; s1[tid]=l1; __syncthreads();
  for (int s=128;s>0;s>>=1){ if (tid<s){ s0[tid]+=s0[tid+s]; s1[tid]+=s1[tid+s]; } __syncthreads(); }
  if (tid==0){
    // n_open = 2*S0, n_dil = 2*S1 (30 distinct channels each counted twice)
    out[0] = (float)(fabs(2.0*(s0[0]-s1[0])) + (double)base[0]);
  }
}

extern "C" void kernel_launch(void* const* d_in, const int* in_sizes, int n_in,
                              void* d_out, int out_size, void* d_ws, size_t ws_size,
                              hipStream_t stream){
  const float* logits = (const float*)d_in[0];
  const float* base   = (const float*)d_in[1];
  float* out = (float*)d_out;

  char* ws = (char*)d_ws;
  size_t off = 0;
  auto alloc = [&](size_t bytes)->char*{
    char* p = ws + off; off = (off + bytes + 255) & ~(size_t)255; return p;
  };
  double* part = (double*)alloc(2048*sizeof(double));   // [2][1024]
  float*  cm   = (float*) alloc((size_t)C30*HP*sizeof(float));
  float*  XP   = (float*) alloc((size_t)TOT*sizeof(float));
  float*  OPN  = (float*) alloc((size_t)TOT*sizeof(float));
  float*  Abuf = (float*) alloc((size_t)TOT*sizeof(float));
  float*  Bbuf = (float*) alloc((size_t)TOT*sizeof(float));
  float*  Cbuf = (float*) alloc((size_t)TOT*sizeof(float));
  (void)ws_size; (void)in_sizes; (void)n_in; (void)out_size;

  dim3 mmGrid((HP+63)/64, (HP+63)/64, C30);   // 5 x 5 x 30
  int eb = (NPIX+255)/256;
  int tb = (TOT+255)/256;

  build_fc_k<<<eb,256,0,stream>>>(logits, XP, OPN);

  // ---- opening: x = maxpoolpad(x) @ XP, twice; then normalize@OPN ----
  pool_pad_k<1><<<tb,256,0,stream>>>(XP, Abuf);
  matmul_k<<<mmGrid,256,0,stream>>>(Abuf, XP, Bbuf);
  pool_pad_k<1><<<tb,256,0,stream>>>(Bbuf, Abuf);
  matmul_k<<<mmGrid,256,0,stream>>>(Abuf, XP, Cbuf);        // operated_open
  normalize_k<<<eb,256,0,stream>>>(Cbuf, Abuf);
  matmul_k<<<mmGrid,256,0,stream>>>(Abuf, OPN, Bbuf);       // x = norm @ operand
  absdiff_reduce_k<<<1024,256,0,stream>>>(OPN, Bbuf, part);

  // ---- dilation: y = avgpoolpad(x) @ XP; rectify; twice; normalize@XP ----
  pool_pad_k<0><<<tb,256,0,stream>>>(XP, Abuf);
  matmul_k<<<mmGrid,256,0,stream>>>(Abuf, XP, Bbuf);        // y1
  colmean_k<<<dim3(2,C30),256,0,stream>>>(Bbuf, XP, cm);
  rectify_k<<<tb,256,0,stream>>>(XP, Bbuf, cm, Cbuf);       // x1
  pool_pad_k<0><<<tb,256,0,stream>>>(Cbuf, Abuf);
  matmul_k<<<mmGrid,256,0,stream>>>(Abuf, XP, Bbuf);        // y2
  colmean_k<<<dim3(2,C30),256,0,stream>>>(Bbuf, Cbuf, cm);
  rectify_k<<<tb,256,0,stream>>>(Cbuf, Bbuf, cm, Abuf);     // x2 = operated_dil
  normalize_k<<<eb,256,0,stream>>>(Abuf, Bbuf);
  matmul_k<<<mmGrid,256,0,stream>>>(Bbuf, XP, Cbuf);        // x = norm @ operand
  absdiff_reduce_k<<<1024,256,0,stream>>>(XP, Cbuf, part + 1024);

  finalize_k<<<1,256,0,stream>>>(part, base, out);
}

// Round 2
// 222.881 us; speedup vs baseline: 2.2095x; 2.2095x over previous
//
#include <hip/hip_runtime.h>
#include <math.h>

#define HP 258
#define NPIX (HP*HP)          // 66564
#define C30 30
#define TOT (C30*NPIX)        // 1996920
#define LOGW 64
#define LDSK 40               // LDS k-stride (bf16 elems): 80 B rows, 16B aligned

typedef __bf16 bf16x8 __attribute__((ext_vector_type(8)));
typedef float  f32x4  __attribute__((ext_vector_type(4)));
typedef unsigned short ushort;
typedef unsigned short ushort8 __attribute__((ext_vector_type(8)));

static __device__ inline ushort f2bf(float f){
  __bf16 h = (__bf16)f;                 // RNE, compiler emits v_cvt_pk_bf16_f32
  return __builtin_bit_cast(ushort, h);
}

// ---------------- build padded fc channels (30 distinct, each x2 in ref) ----
// XP  = pad1(fc) fp32; XPbf/OPNbf = bf16 copies of pad1(fc)/pad1(-fc) for MFMA B
__global__ void build_fc_k(const float* __restrict__ logits,
                           float* __restrict__ xp, float* __restrict__ opn,
                           ushort* __restrict__ xpbf, ushort* __restrict__ opnbf){
  int p = blockIdx.x*256 + threadIdx.x;
  if (p >= NPIX) return;
  int h = p / HP, w = p % HP;
  if (h==0 || h==HP-1 || w==0 || w==HP-1){
    ushort one = f2bf(1.0f);
    #pragma unroll
    for (int c=0;c<C30;c++){
      xp[c*NPIX+p] = 1.0f; opn[c*NPIX+p] = 1.0f;
      xpbf[c*NPIX+p] = one; opnbf[c*NPIX+p] = one;
    }
    return;
  }
  int oh = h-1, ow = w-1;
  float fy = 0.25f*oh - 0.375f;
  float fx = 0.25f*ow - 0.375f;
  float y0f = floorf(fy), x0f = floorf(fx);
  float ty = fy - y0f, tx = fx - x0f;
  int y0 = max(0, (int)y0f), y1 = min(LOGW-1, (int)y0f + 1);
  int x0 = max(0, (int)x0f), x1 = min(LOGW-1, (int)x0f + 1);
  float s[6];
  float m = -3.402823466e+38f;
  #pragma unroll
  for (int c=0;c<6;c++){
    const float* pl = logits + c*LOGW*LOGW;
    float v00 = pl[y0*LOGW + x0], v01 = pl[y0*LOGW + x1];
    float v10 = pl[y1*LOGW + x0], v11 = pl[y1*LOGW + x1];
    float a = v00 + (v01 - v00)*tx;
    float b = v10 + (v11 - v10)*tx;
    float v = a + (b - a)*ty;
    s[c] = v; m = fmaxf(m, v);
  }
  float sum = 0.0f;
  #pragma unroll
  for (int c=0;c<6;c++){ s[c] = expf(s[c]-m); sum += s[c]; }
  float inv = 1.0f/sum;
  #pragma unroll
  for (int c=0;c<6;c++) s[c] *= inv;
  #pragma unroll
  for (int c=0;c<C30;c++){
    int i = c/5, r = c%5;
    int j = r + (r>=i ? 1 : 0);      // itertools.permutations order
    float d = 0.5f*(s[i]-s[j]);
    float v = fmaxf(d, 0.0f);
    xp[c*NPIX+p]  = v;
    opn[c*NPIX+p] = -v;
    xpbf[c*NPIX+p]  = f2bf(v);
    opnbf[c*NPIX+p] = f2bf(-v);
  }
}

// ---------------- 3x3 pool (VALID) then pad1 with 1.0 ----------------------
template<int MAXP>
__global__ void pool_pad_k(const float* __restrict__ src, float* __restrict__ dst){
  int idx = blockIdx.x*256 + threadIdx.x;
  if (idx >= TOT) return;
  int c = idx / NPIX, p = idx % NPIX;
  int h = p / HP, w = p % HP;
  if (h==0 || h==HP-1 || w==0 || w==HP-1){ dst[idx] = 1.0f; return; }
  const float* s = src + (size_t)c*NPIX;
  if (MAXP){
    float mv = -3.402823466e+38f;
    #pragma unroll
    for (int dy=-1;dy<=1;dy++)
      #pragma unroll
      for (int dx=-1;dx<=1;dx++)
        mv = fmaxf(mv, s[(h+dy)*HP + (w+dx)]);
    dst[idx] = mv;
  } else {
    float a = 0.0f;
    #pragma unroll
    for (int dy=-1;dy<=1;dy++)
      #pragma unroll
      for (int dx=-1;dx<=1;dx++)
        a += s[(h+dy)*HP + (w+dx)];
    dst[idx] = a / 9.0f;
  }
}

// ---------------- batched MFMA matmul: C[ch] = A[ch](fp32) @ B[ch](bf16) ----
// 64x64 tile, BK=32, 4 waves each owning a 32x32 quadrant (2x2 of 16x16x32).
__global__ __launch_bounds__(256) void mm_mfma_k(const float* __restrict__ A,
                                                 const ushort* __restrict__ Bbf,
                                                 float* __restrict__ C){
  __shared__ ushort As[64*LDSK];   // [row][k]
  __shared__ ushort Bs[64*LDSK];   // [col][k] (transposed)
  int ch = blockIdx.z;
  const float*  Ab = A   + (size_t)ch*NPIX;
  const ushort* Bb = Bbf + (size_t)ch*NPIX;
  float*        Cb = C   + (size_t)ch*NPIX;
  int tid = threadIdx.x;
  int lane = tid & 63, wv = tid >> 6;
  int wr = (wv >> 1)*32, wc = (wv & 1)*32;
  int rowBase = blockIdx.x*64, colBase = blockIdx.y*64;
  int l15 = lane & 15, lq = lane >> 4;

  f32x4 acc00 = {0.f,0.f,0.f,0.f}, acc01 = acc00, acc10 = acc00, acc11 = acc00;

  int arow = tid >> 2, akb = (tid & 3)*8;   // A: 64 rows x 32 k, 8 k per thread
  int bn   = tid & 63, bkb = (tid >> 6)*8;  // B: 64 cols, 8 k per thread (gather)
  int agr = rowBase + arow;
  int bgc = colBase + bn;

  for (int k0 = 0; k0 < HP; k0 += 32){
    // ---- stage A (fp32 -> bf16, row-major) ----
    {
      int gk = k0 + akb;
      ushort8 t8;
      if (agr < HP && gk + 8 <= HP){
        const float* p = Ab + (size_t)agr*HP + gk;   // 8B aligned
        float2 f0 = *(const float2*)(p+0);
        float2 f1 = *(const float2*)(p+2);
        float2 f2 = *(const float2*)(p+4);
        float2 f3 = *(const float2*)(p+6);
        t8[0]=f2bf(f0.x); t8[1]=f2bf(f0.y);
        t8[2]=f2bf(f1.x); t8[3]=f2bf(f1.y);
        t8[4]=f2bf(f2.x); t8[5]=f2bf(f2.y);
        t8[6]=f2bf(f3.x); t8[7]=f2bf(f3.y);
      } else {
        #pragma unroll
        for (int i=0;i<8;i++){
          int kk = gk + i;
          float v = (agr < HP && kk < HP) ? Ab[(size_t)agr*HP + kk] : 0.0f;
          t8[i] = f2bf(v);
        }
      }
      *(ushort8*)(&As[arow*LDSK + akb]) = t8;
    }
    // ---- stage B (bf16, transpose to [col][k]) ----
    {
      ushort8 t8;
      if (bgc < HP && k0 + bkb + 8 <= HP){
        #pragma unroll
        for (int i=0;i<8;i++)
          t8[i] = Bb[(size_t)(k0 + bkb + i)*HP + bgc];
      } else {
        #pragma unroll
        for (int i=0;i<8;i++){
          int kk = k0 + bkb + i;
          t8[i] = (bgc < HP && kk < HP) ? Bb[(size_t)kk*HP + bgc] : (ushort)0;
        }
      }
      *(ushort8*)(&Bs[bn*LDSK + bkb]) = t8;
    }
    __syncthreads();
    bf16x8 a0 = __builtin_bit_cast(bf16x8, *(const ushort8*)(&As[(wr      + l15)*LDSK + lq*8]));
    bf16x8 a1 = __builtin_bit_cast(bf16x8, *(const ushort8*)(&As[(wr + 16 + l15)*LDSK + lq*8]));
    bf16x8 b0 = __builtin_bit_cast(bf16x8, *(const ushort8*)(&Bs[(wc      + l15)*LDSK + lq*8]));
    bf16x8 b1 = __builtin_bit_cast(bf16x8, *(const ushort8*)(&Bs[(wc + 16 + l15)*LDSK + lq*8]));
    acc00 = __builtin_amdgcn_mfma_f32_16x16x32_bf16(a0, b0, acc00, 0, 0, 0);
    acc01 = __builtin_amdgcn_mfma_f32_16x16x32_bf16(a0, b1, acc01, 0, 0, 0);
    acc10 = __builtin_amdgcn_mfma_f32_16x16x32_bf16(a1, b0, acc10, 0, 0, 0);
    acc11 = __builtin_amdgcn_mfma_f32_16x16x32_bf16(a1, b1, acc11, 0, 0, 0);
    __syncthreads();
  }
  // epilogue: C/D layout col = lane&15, row = (lane>>4)*4 + reg  [m89]
  auto store = [&](f32x4 v, int r0, int c0){
    if (c0 < HP){
      #pragma unroll
      for (int r=0;r<4;r++){
        int rr = r0 + r;
        if (rr < HP) Cb[(size_t)rr*HP + c0] = v[r];
      }
    }
  };
  store(acc00, rowBase + wr +      lq*4, colBase + wc +      l15);
  store(acc01, rowBase + wr +      lq*4, colBase + wc + 16 + l15);
  store(acc10, rowBase + wr + 16 + lq*4, colBase + wc +      l15);
  store(acc11, rowBase + wr + 16 + lq*4, colBase + wc + 16 + l15);
}

// ---------------- column mean over rows (axis=2) of (y - x) -----------------
__global__ void colmean_k(const float* __restrict__ y, const float* __restrict__ x,
                          float* __restrict__ cm){
  int c = blockIdx.y;
  int w = blockIdx.x*256 + threadIdx.x;
  if (w >= HP) return;
  const float* yb = y + (size_t)c*NPIX;
  const float* xb = x + (size_t)c*NPIX;
  float sum = 0.0f;
  for (int h=0; h<HP; h++) sum += yb[h*HP+w] - xb[h*HP+w];
  cm[c*HP + w] = sum / (float)HP;
}

// ---------------- rectification: out = x + relu((y-x) - colmean) ------------
__global__ void rectify_k(const float* __restrict__ x, const float* __restrict__ y,
                          const float* __restrict__ cm, float* __restrict__ out){
  int idx = blockIdx.x*256 + threadIdx.x;
  if (idx >= TOT) return;
  int c = idx / NPIX, p = idx % NPIX;
  int w = p % HP;
  float xv = x[idx];
  float off = y[idx] - xv - cm[c*HP + w];
  out[idx] = xv + fmaxf(off, 0.0f);
}

// ---------------- channel-normalize (60 ch == 2x the 30 distinct) -----------
__global__ void normalize_k(const float* __restrict__ oper, float* __restrict__ out){
  int p = blockIdx.x*256 + threadIdx.x;
  if (p >= NPIX) return;
  float ss = 0.0f;
  #pragma unroll
  for (int c=0;c<C30;c++){ float v = oper[c*NPIX+p]; ss = fmaf(v,v,ss); }
  float n = sqrtf(2.0f*ss);                // duplicate channels double sum-sq
  float inv = 1.0f / fmaxf(n, 1e-12f);
  #pragma unroll
  for (int c=0;c<C30;c++) out[c*NPIX+p] = oper[c*NPIX+p] * inv;
}

// ---------------- sum |a-b| -> deterministic per-block partials -------------
__global__ void absdiff_reduce_k(const float* __restrict__ a, const float* __restrict__ b,
                                 double* __restrict__ part){
  __shared__ double sd[256];
  int tid = threadIdx.x;
  size_t i = (size_t)blockIdx.x*256 + tid;
  size_t stride = (size_t)gridDim.x*256;
  double local = 0.0;
  for (; i < (size_t)TOT; i += stride) local += (double)fabsf(a[i]-b[i]);
  sd[tid] = local;
  __syncthreads();
  for (int s=128; s>0; s>>=1){ if (tid<s) sd[tid]+=sd[tid+s]; __syncthreads(); }
  if (tid==0) part[blockIdx.x] = sd[0];
}

// ---------------- final: |n_open - n_dil| + base_loss -----------------------
__global__ void finalize_k(const double* __restrict__ part,
                           const float* __restrict__ base, float* __restrict__ out){
  __shared__ double s0[256], s1[256];
  int tid = threadIdx.x;
  double l0=0.0, l1=0.0;
  for (int i=tid;i<1024;i+=256){ l0 += part[i]; l1 += part[1024+i]; }
  s0[tid]=l0; s1[tid]=l1; __syncthreads();
  for (int s=128;s>0;s>>=1){ if (tid<s){ s0[tid]+=s0[tid+s]; s1[tid]+=s1[tid+s]; } __syncthreads(); }
  if (tid==0){
    out[0] = (float)(fabs(2.0*(s0[0]-s1[0])) + (double)base[0]);
  }
}

extern "C" void kernel_launch(void* const* d_in, const int* in_sizes, int n_in,
                              void* d_out, int out_size, void* d_ws, size_t ws_size,
                              hipStream_t stream){
  const float* logits = (const float*)d_in[0];
  const float* base   = (const float*)d_in[1];
  float* out = (float*)d_out;

  char* ws = (char*)d_ws;
  size_t off = 0;
  auto alloc = [&](size_t bytes)->char*{
    char* p = ws + off; off = (off + bytes + 255) & ~(size_t)255; return p;
  };
  double* part  = (double*)alloc(2048*sizeof(double));   // [2][1024]
  float*  cm    = (float*) alloc((size_t)C30*HP*sizeof(float));
  float*  XP    = (float*) alloc((size_t)TOT*sizeof(float));
  float*  OPN   = (float*) alloc((size_t)TOT*sizeof(float));
  ushort* XPbf  = (ushort*)alloc((size_t)TOT*sizeof(ushort));
  ushort* OPNbf = (ushort*)alloc((size_t)TOT*sizeof(ushort));
  float*  Abuf  = (float*) alloc((size_t)TOT*sizeof(float));
  float*  Bbuf  = (float*) alloc((size_t)TOT*sizeof(float));
  float*  Cbuf  = (float*) alloc((size_t)TOT*sizeof(float));
  (void)ws_size; (void)in_sizes; (void)n_in; (void)out_size;

  dim3 mmGrid((HP+63)/64, (HP+63)/64, C30);   // 5 x 5 x 30
  int eb = (NPIX+255)/256;
  int tb = (TOT+255)/256;

  build_fc_k<<<eb,256,0,stream>>>(logits, XP, OPN, XPbf, OPNbf);

  // ---- opening: x = maxpoolpad(x) @ XP, twice; then normalize @ OPN ----
  pool_pad_k<1><<<tb,256,0,stream>>>(XP, Abuf);
  mm_mfma_k<<<mmGrid,256,0,stream>>>(Abuf, XPbf, Bbuf);
  pool_pad_k<1><<<tb,256,0,stream>>>(Bbuf, Abuf);
  mm_mfma_k<<<mmGrid,256,0,stream>>>(Abuf, XPbf, Cbuf);     // operated_open
  normalize_k<<<eb,256,0,stream>>>(Cbuf, Abuf);
  mm_mfma_k<<<mmGrid,256,0,stream>>>(Abuf, OPNbf, Bbuf);    // x = norm @ operand
  absdiff_reduce_k<<<1024,256,0,stream>>>(OPN, Bbuf, part);

  // ---- dilation: y = avgpoolpad(x) @ XP; rectify; twice; normalize @ XP ----
  pool_pad_k<0><<<tb,256,0,stream>>>(XP, Abuf);
  mm_mfma_k<<<mmGrid,256,0,stream>>>(Abuf, XPbf, Bbuf);     // y1
  colmean_k<<<dim3(2,C30),256,0,stream>>>(Bbuf, XP, cm);
  rectify_k<<<tb,256,0,stream>>>(XP, Bbuf, cm, Cbuf);       // x1
  pool_pad_k<0><<<tb,256,0,stream>>>(Cbuf, Abuf);
  mm_mfma_k<<<mmGrid,256,0,stream>>>(Abuf, XPbf, Bbuf);     // y2
  colmean_k<<<dim3(2,C30),256,0,stream>>>(Bbuf, Cbuf, cm);
  rectify_k<<<tb,256,0,stream>>>(Cbuf, Bbuf, cm, Abuf);     // x2 = operated_dil
  normalize_k<<<eb,256,0,stream>>>(Abuf, Bbuf);
  mm_mfma_k<<<mmGrid,256,0,stream>>>(Bbuf, XPbf, Cbuf);     // x = norm @ operand
  absdiff_reduce_k<<<1024,256,0,stream>>>(XP, Cbuf, part + 1024);

  finalize_k<<<1,256,0,stream>>>(part, base, out);
}